// Round 6
// baseline (251.019 us; speedup 1.0000x reference)
//
#include <hip/hip_runtime.h>

#define DCH    512
#define RPB    16                 // output rows per tile
#define WROWS  (RPB + 6)          // 22 staged rows per tile (halo 3+3)
#define BUFF   (WROWS * DCH)      // 11264 floats = 45056 B per buffer
#define CHUNKS (WROWS * 2)        // 44 chunks of 1 KB (64 lanes x 16 B)
#define NWAVE  4
#define TPW    (CHUNKS / NWAVE)   // 11 global_load_lds per wave per tile
#define NBLK   256                // 1 block per CU (LDS-limited anyway)

typedef float f32x2 __attribute__((ext_vector_type(2)));

// Counted vmcnt + scheduling fence (rule 18).
__device__ __forceinline__ void vmwait(int n) {
    switch (n) {
        case 0:  asm volatile("s_waitcnt vmcnt(0)"  ::: "memory"); break;
        case 22: asm volatile("s_waitcnt vmcnt(22)" ::: "memory"); break;
        case 38: asm volatile("s_waitcnt vmcnt(38)" ::: "memory"); break;
        default: asm volatile("s_waitcnt vmcnt(54)" ::: "memory"); break;
    }
    __builtin_amdgcn_sched_barrier(0);
}

// Stage one tile (22 rows) into an LDS buffer via global->LDS DMA.
// No VGPR destinations -> the compiler cannot sink or spill these loads
// (the R0-R5 failure mode). Out-of-array rows are staged CLAMPED (finite
// garbage): every out-of-array tap is already mask-zeroed by the bag
// logic, and uniform 11-loads/wave keeps the vmcnt ledger exact.
__device__ __forceinline__ void stage_tile(const float* __restrict__ x,
                                           float* lbase, int r0, int n_rows,
                                           int wid, int lane)
{
    #pragma unroll
    for (int s = 0; s < TPW; ++s) {
        const int c = wid + NWAVE * s;        // chunk 0..43, wave-strided
        int row = r0 - 3 + (c >> 1);          // global row of this chunk
        row = row < 0 ? 0 : (row >= n_rows ? n_rows - 1 : row);
        const float* g = x + (size_t)row * DCH + (c & 1) * 256 + lane * 4;
        float* l = lbase + c * 256;           // LDS dest: base + lane*16 implicit
        __builtin_amdgcn_global_load_lds(
            (const __attribute__((address_space(1))) void*)g,
            (__attribute__((address_space(3))) void*)l, 16, 0, 0);
    }
}

__global__ __launch_bounds__(256) void ppeg_dwconv_kernel(
    const float* __restrict__ x,
    const float* __restrict__ w3, const float* __restrict__ b3,
    const float* __restrict__ w5, const float* __restrict__ b5,
    const float* __restrict__ w7, const float* __restrict__ b7,
    const int* __restrict__ lengths,
    float* __restrict__ out, int n_rows, int n_bags)
{
    __shared__ float lbuf[3][BUFF];   // 132 KB triple buffer
    __shared__ int soff[40];          // bag prefix offsets

    const int tid  = threadIdx.x;
    const int wid  = tid >> 6;
    const int lane = tid & 63;
    const int c0   = tid * 2;         // this thread's 2 channels

    if (tid == 0) {
        int acc = 0;
        for (int i = 0; i < n_bags; ++i) { soff[i] = acc; acc += lengths[i]; }
        soff[n_bags] = acc;
    }

    // Folded 7-tap weights (loads fully consumed before the pipeline, so the
    // vmcnt ledger below sees only stage loads + our stores).
    float W[7][2], bias[2];
    #pragma unroll
    for (int q2 = 0; q2 < 2; ++q2) {
        const int d = c0 + q2;
        const float a0 = w7[d*7+0], a1 = w7[d*7+1], a2 = w7[d*7+2], a3 = w7[d*7+3],
                    a4 = w7[d*7+4], a5 = w7[d*7+5], a6 = w7[d*7+6];
        const float f0 = w5[d*5+0], f1 = w5[d*5+1], f2 = w5[d*5+2], f3 = w5[d*5+3], f4 = w5[d*5+4];
        const float e0 = w3[d*3+0], e1 = w3[d*3+1], e2 = w3[d*3+2];
        W[0][q2] = a0;
        W[1][q2] = a1 + f0;
        W[2][q2] = a2 + f1 + e0;
        W[3][q2] = a3 + f2 + e1 + 1.0f;
        W[4][q2] = a4 + f3 + e2;
        W[5][q2] = a5 + f4;
        W[6][q2] = a6;
        bias[q2] = b3[d] + b5[d] + b7[d];
    }

    // Full sync (vmcnt(0)+lgkmcnt(0)+barrier): weight loads drained, soff
    // visible. The ONLY __syncthreads in the kernel — inside the pipeline
    // we use raw s_barrier so in-flight stages survive the barrier.
    __syncthreads();

    // Contiguous tile range per block (chunked => XCD-L2-local by layout).
    const int ntiles = (n_rows + RPB - 1) / RPB;
    const int nblk   = gridDim.x;
    const int q      = ntiles / nblk, rem = ntiles % nblk;
    const int bidx   = blockIdx.x;
    const int T      = q + (bidx < rem ? 1 : 0);
    const int t0     = bidx * q + (bidx < rem ? bidx : rem);
    if (T <= 0) return;

    // Prologue: 2 tiles ahead.
    stage_tile(x, &lbuf[0][0], t0 * RPB, n_rows, wid, lane);
    if (T > 1) stage_tile(x, &lbuf[1][0], (t0 + 1) * RPB, n_rows, wid, lane);

    for (int k = 0; k < T; ++k) {
        const int r0 = (t0 + k) * RPB;

        // Stage tile k+2 (buffer computed at iter k-1; freed by its trailing
        // barrier).
        if (k + 2 < T)
            stage_tile(x, &lbuf[(k + 2) % 3][0], (t0 + k + 2) * RPB, n_rows, wid, lane);

        // Bag search for this tile (uniform; soff is read-only after init).
        int b = 0;
        #pragma unroll
        for (int s = 16; s >= 1; s >>= 1)
            if (b + s < n_bags && soff[b + s] <= r0) b += s;
        const int e0b = soff[b];
        const int e1b = soff[b + 1];
        const int e2b = (b + 2 <= n_bags) ? soff[b + 2] : e1b;

        // Counted wait: need MY stage(k) loads retired. Younger ops per wave:
        // stores(k-2)16 + stage(k+1)11 + stores(k-1)16 + stage(k+2)11 = 54
        // steady; 22 at k=0; 38 at k=1; full drain for the last two tiles
        // (keeps the ledger safe if the tail tile skips stores).
        const int w = (k + 2 < T) ? (k == 0 ? 22 : (k == 1 ? 38 : 54)) : 0;
        vmwait(w);
        __builtin_amdgcn_s_barrier();          // all waves' stage(k) visible
        __builtin_amdgcn_sched_barrier(0);

        const float* lb = &lbuf[k % 3][0];
        float*       ob = out + (size_t)r0 * DCH + c0;

        #pragma unroll
        for (int i = 0; i < RPB; ++i) {
            const int r = r0 + i;

            const bool nb   = (r >= e1b);      // row fell into next bag
            const int  offb = nb ? e1b : e0b;
            const int  endb = nb ? e2b : e1b;
            const int  t    = r - offb - 1;    // body position; -1 => cls
            const int  Lb1  = endb - offb - 1; // body length

            // Window rows i..i+6 from LDS (8 B/lane, stride-8 contiguous:
            // 2-way bank aliasing = free per m136).
            f32x2 v[7];
            #pragma unroll
            for (int dt = 0; dt < 7; ++dt)
                v[dt] = *(const f32x2*)(lb + (i + dt) * DCH + c0);

            f32x2 o;
            if (t < 0) {
                o = v[3];                      // cls row: pass-through
            } else if (t >= 3 && t + 3 < Lb1) {
                float a0 = bias[0], a1 = bias[1];
                #pragma unroll
                for (int dt = 0; dt < 7; ++dt) {
                    a0 = fmaf(W[dt][0], v[dt].x, a0);
                    a1 = fmaf(W[dt][1], v[dt].y, a1);
                }
                o = (f32x2){a0, a1};
            } else {
                // Bag-edge: masked taps reproduce zero padding AND zero any
                // clamped out-of-array staging (mm*W finite, v finite).
                float a0 = bias[0], a1 = bias[1];
                #pragma unroll
                for (int dt = 0; dt < 7; ++dt) {
                    const int  tp    = t + dt - 3;
                    const float mm   = (tp >= 0 && tp < Lb1) ? 1.0f : 0.0f;
                    a0 = fmaf(mm * W[dt][0], v[dt].x, a0);
                    a1 = fmaf(mm * W[dt][1], v[dt].y, a1);
                }
                o = (f32x2){a0, a1};
            }

            if (r < n_rows)
                __builtin_nontemporal_store(o, (f32x2*)(ob + (size_t)i * DCH));
        }

        // My LDS reads of buf k%3 complete, then block-wide sync: buffer is
        // free for re-staging at iter k+1. lgkmcnt only — vmcnt untouched,
        // stage(k+1)/(k+2) stay in flight across the barrier.
        asm volatile("s_waitcnt lgkmcnt(0)" ::: "memory");
        __builtin_amdgcn_s_barrier();
        __builtin_amdgcn_sched_barrier(0);
    }
}

extern "C" void kernel_launch(void* const* d_in, const int* in_sizes, int n_in,
                              void* d_out, int out_size, void* d_ws, size_t ws_size,
                              hipStream_t stream) {
    const float* x       = (const float*)d_in[0];
    const float* w3      = (const float*)d_in[1];
    const float* b3      = (const float*)d_in[2];
    const float* w5      = (const float*)d_in[3];
    const float* b5      = (const float*)d_in[4];
    const float* w7      = (const float*)d_in[5];
    const float* b7      = (const float*)d_in[6];
    const int*   lengths = (const int*)d_in[7];

    const int n_bags = in_sizes[7];
    const int n_rows = in_sizes[0] / DCH;
    float* out = (float*)d_out;

    const int ntiles = (n_rows + RPB - 1) / RPB;
    const int nblk   = ntiles < NBLK ? ntiles : NBLK;
    ppeg_dwconv_kernel<<<nblk, 256, 0, stream>>>(
        x, w3, b3, w5, b5, w7, b7, lengths, out, n_rows, n_bags);
}